// Round 17
// baseline (216.308 us; speedup 1.0000x reference)
//
#include <hip/hip_runtime.h>

#define NN 200000
#define EE (NN - 1)
#define NSTEPS 4
#define DTC 0.01f
#define WPB 4
#define NPB 128           // nodes per block (2 tiles of 16 per wave x 4 waves)
#define GRID 1563         // ceil(200000/128)

typedef __attribute__((ext_vector_type(8))) _Float16 f16x8;
typedef __attribute__((ext_vector_type(2))) _Float16 f16x2;
typedef __attribute__((ext_vector_type(4))) float f32x4;

struct H4 { f16x2 a, b, c, d; };

__device__ __forceinline__ f16x2 c2h(float lo, float hi) {
    return __builtin_bit_cast(f16x2, __builtin_amdgcn_cvt_pkrtz(lo, hi)); // 1 instr
}
__device__ __forceinline__ unsigned pk2h(float lo, float hi) {
    return __builtin_bit_cast(unsigned, __builtin_amdgcn_cvt_pkrtz(lo, hi));
}
__device__ __forceinline__ f16x8 h8(f16x2 a, f16x2 b, f16x2 c, f16x2 d) {
    H4 t{a, b, c, d};
    return __builtin_bit_cast(f16x8, t);
}
__device__ __forceinline__ f16x2 relu2(f16x2 v) {   // v_pk_max_f16 vs 0
    f16x2 r;
    asm("v_pk_max_f16 %0, %1, 0" : "=v"(r) : "v"(v));
    return r;
}
__device__ __forceinline__ float swishf(float x) { return x / (1.0f + __expf(-x)); }

// dimension relabeling (verified R8+): C output (ct,q,r) packs directly into
// the next GEMM's B operand slots; B pos k <-> original dim permk(k).
__device__ __forceinline__ int permk(int k) {
    return (k & 0x23) | ((k & 4) << 2) | ((k & 0x18) >> 1);
}

// set dword 3 (f16 pair 3) of an f16x8 where cond holds: 1 v_cndmask
__device__ __forceinline__ f16x8 setw(f16x8 v, bool cond, unsigned nw) {
    uint4 u = __builtin_bit_cast(uint4, v);
    u.w = cond ? nw : u.w;
    return __builtin_bit_cast(f16x8, u);
}

// ws layout (ushort offsets within the weight region):
// [0,4096) w1s ; [4096,8192) w2s ; [8192,8704) encN ; [8704,9216) encE ;
// [9216,9728) dW1 ; [9728,10240) dW2 ; [10240,11264) outW
__global__ void gnode_weights(const float* __restrict__ ode_w1, const float* __restrict__ ode_b1,
                              const float* __restrict__ ode_w2, const float* __restrict__ ode_b2,
                              const float* __restrict__ enc_n_w2, const float* __restrict__ enc_e_w2,
                              const float* __restrict__ dec_n_w1, const float* __restrict__ dec_n_w2,
                              const float* __restrict__ node_out_w,
                              unsigned short* __restrict__ wg)
{
    const int b = blockIdx.x;
    const int tid = threadIdx.x;
    if (b < 8) {                     // W1ext^T / W2ext^T, permuted columns
        const int i = tid + b * 256;
        const int od = i >> 5;
        const int k2 = (i & 31) * 2;
        const int s0 = permk(k2);
        const int s1 = s0 + 1;
        float a0 = 0.f, a1 = 0.f, b0 = 0.f, b1 = 0.f;
        if (od < 50) {
            a0 = (s0 <= 50) ? ode_w1[s0 * 50 + od] : 0.f;
            a1 = (s1 <= 50) ? ode_w1[s1 * 50 + od]
                            : ((s1 == 51) ? ode_b1[od] : 0.f);
            b0 = (s0 < 50) ? ode_w2[s0 * 50 + od]
                           : ((s0 == 50) ? ode_b2[od] : 0.f);
            b1 = (s1 < 50) ? ode_w2[s1 * 50 + od] : 0.f;
        }
        *(unsigned*)(wg + od * 64 + k2) = pk2h(a0, a1);
        *(unsigned*)(wg + 4096 + od * 64 + k2) = pk2h(b0, b1);
    } else if (b < 10) {             // node_out_w^T 16x64, permuted cols
        const int i = tid + (b - 8) * 256;
        const int mm = i >> 5;
        const int kp = (i & 31) * 2;
        const int s0 = permk(kp);
        const float v0 = (s0     < 50) ? node_out_w[s0 * 16 + mm] : 0.f;
        const float v1 = (s0 + 1 < 50) ? node_out_w[(s0 + 1) * 16 + mm] : 0.f;
        *(unsigned*)(wg + 10240 + mm * 64 + kp) = pk2h(v0, v1);
    } else {                         // enc/dec 16x32 tiles, natural k (k>=16 zero)
        const int mm = tid >> 4;
        const int kp = (tid & 15) * 2;
        const bool rl = (kp < 16);
        const float eN0 = rl ? enc_n_w2[kp * 16 + mm] : 0.f;
        const float eN1 = rl ? enc_n_w2[(kp + 1) * 16 + mm] : 0.f;
        const float eE0 = rl ? enc_e_w2[kp * 16 + mm] : 0.f;
        const float eE1 = rl ? enc_e_w2[(kp + 1) * 16 + mm] : 0.f;
        const float d10 = rl ? dec_n_w1[kp * 16 + mm] : 0.f;
        const float d11 = rl ? dec_n_w1[(kp + 1) * 16 + mm] : 0.f;
        const float d20 = rl ? dec_n_w2[kp * 16 + mm] : 0.f;
        const float d21 = rl ? dec_n_w2[(kp + 1) * 16 + mm] : 0.f;
        *(unsigned*)(wg + 8192 + mm * 32 + kp) = pk2h(eN0, eN1);
        *(unsigned*)(wg + 8704 + mm * 32 + kp) = pk2h(eE0, eE1);
        *(unsigned*)(wg + 9216 + mm * 32 + kp) = pk2h(d10, d11);
        *(unsigned*)(wg + 9728 + mm * 32 + kp) = pk2h(d20, d21);
    }
}

// R17: R16 code verbatim, launch_bounds(256,4). Hypothesis: R16's 24%
// occupancy is capped by total VGPR+AGPR (~80 arch + ~64 acc = 144 -> 3
// waves/SIMD), and the (256,4) budget (128 total) pushes the allocator to a
// 4-wave-resident allocation. Counters disambiguate: spill mode = VGPR 64 +
// WRITE_SIZE >> 50 MB (then revert to R16 and declare ceiling).
__global__ __launch_bounds__(256, 4)
void gnode_main(const float* __restrict__ nodes,
                const float* __restrict__ edges,
                const float* __restrict__ g,
                const float* __restrict__ enc_n_w1, const float* __restrict__ enc_n_b1,
                const float* __restrict__ enc_n_b2,
                const float* __restrict__ enc_e_w1, const float* __restrict__ enc_e_b1,
                const float* __restrict__ enc_e_b2,
                const float* __restrict__ node_out_b,
                const float* __restrict__ dec_n_b1, const float* __restrict__ dec_n_b2,
                const float* __restrict__ dec_n_w3, const float* __restrict__ dec_n_b3,
                const unsigned short* __restrict__ wg,
                float* __restrict__ out, float* __restrict__ npos)
{
    __shared__ __attribute__((aligned(16))) unsigned short dscr[WPB][640];

    const int tid  = threadIdx.x;
    const int lane = tid & 63;
    const int wave = __builtin_amdgcn_readfirstlane(tid >> 6);
    const int m = lane & 15;
    const int q = lane >> 4;
    const bool q0 = (q == 0);
    unsigned short* const dscrw = &dscr[wave][0];

    int nd[2], nc[2];
    nd[0] = blockIdx.x * NPB + wave * 32 + m;
    nd[1] = nd[0] + 16;
    nc[0] = (nd[0] < NN) ? nd[0] : (NN - 1);
    nc[1] = (nd[1] < NN) ? nd[1] : (NN - 1);

    // zero decoder-scratch k=16..31 (dw1/dw2 A-rows are zero there, but LDS
    // garbage could be NaN; 0 * NaN != 0)
    *(uint2*)(dscrw + m * 40 + 16 + q * 4) = make_uint2(0u, 0u);

    // ====== pin ODE weight A-frags (the ONLY loop-live weight registers) =====
    f16x8 w1f[2][4], w2f[2][4];
#pragma unroll
    for (int kt = 0; kt < 2; ++kt)
#pragma unroll
        for (int ct = 0; ct < 4; ++ct) {
            const int od = ct * 16 + m;
            w1f[kt][ct] = *(const f16x8*)(const void*)(wg + od * 64 + kt * 32 + q * 8);
            w2f[kt][ct] = *(const f16x8*)(const void*)(wg + 4096 + od * 64 + kt * 32 + q * 8);
        }

    const f32x4 zero4 = {0.f, 0.f, 0.f, 0.f};
    const f16x2 h2z = {(_Float16)0.f, (_Float16)0.f};
    const f16x8 z8 = h8(h2z, h2z, h2z, h2z);

    // state: Y/ACC/A as whole f16x8 (2 per tile). pair 3 of [..][1] holds the
    // special slots (dims 50,51 = t, bias-1) on q0 lanes.
    f16x8 Y[2][2], ACC[2][2], A[2][2];

    // ---------------- encoder (3 f16 MFMAs per tile) ----------------
    {
        const f16x8 wNf = *(const f16x8*)(const void*)(wg + 8192 + m * 32 + q * 8);
        const f16x8 wEf = *(const f16x8*)(const void*)(wg + 8704 + m * 32 + q * 8);
        f32x4 bN, bE;
#pragma unroll
        for (int r = 0; r < 4; ++r) { bN[r] = enc_n_b2[q * 4 + r]; bE[r] = enc_e_b2[q * 4 + r]; }
        const float g0v = g[0], g1v = g[1];

#pragma unroll
        for (int tt = 0; tt < 2; ++tt) {
            const int node = nc[tt];
            f32x4 e0, e1, e2;
            {
                float nf[5];
#pragma unroll
                for (int c = 0; c < 5; ++c) nf[c] = nodes[node * 5 + c];
                f16x8 bfr = z8;
                if (q < 2) {
                    float hv[8];
#pragma unroll
                    for (int j = 0; j < 8; ++j) {
                        const int d = q * 8 + j;
                        float s = enc_n_b1[d];
#pragma unroll
                        for (int c = 0; c < 5; ++c) s = fmaf(nf[c], enc_n_w1[c * 16 + d], s);
                        hv[j] = swishf(s);
                    }
                    bfr = h8(c2h(hv[0], hv[1]), c2h(hv[2], hv[3]),
                             c2h(hv[4], hv[5]), c2h(hv[6], hv[7]));
                }
                e0 = __builtin_amdgcn_mfma_f32_16x16x32_f16(wNf, bfr, bN, 0, 0, 0);
            }
            {
                const float ev = (node < EE) ? edges[node] : 0.0f;
                f16x8 bfr = z8;
                if (q < 2) {
                    float hv[8];
#pragma unroll
                    for (int j = 0; j < 8; ++j) {
                        const int d = q * 8 + j;
                        hv[j] = swishf(fmaf(ev, enc_e_w1[d], enc_e_b1[d]));
                    }
                    bfr = h8(c2h(hv[0], hv[1]), c2h(hv[2], hv[3]),
                             c2h(hv[4], hv[5]), c2h(hv[6], hv[7]));
                }
                e1 = __builtin_amdgcn_mfma_f32_16x16x32_f16(wEf, bfr, bE, 0, 0, 0);
                if (node == NN - 1) e1 = zero4;
            }
            {
                const float ev = (node > 0) ? edges[node - 1] : 0.0f;
                f16x8 bfr = z8;
                if (q < 2) {
                    float hv[8];
#pragma unroll
                    for (int j = 0; j < 8; ++j) {
                        const int d = q * 8 + j;
                        hv[j] = swishf(fmaf(ev, enc_e_w1[d], enc_e_b1[d]));
                    }
                    bfr = h8(c2h(hv[0], hv[1]), c2h(hv[2], hv[3]),
                             c2h(hv[4], hv[5]), c2h(hv[6], hv[7]));
                }
                e2 = __builtin_amdgcn_mfma_f32_16x16x32_f16(wEf, bfr, bE, 0, 0, 0);
                if (node == 0) e2 = zero4;
            }
            Y[tt][0] = h8(c2h(e0[0], e0[1]), c2h(e0[2], e0[3]),
                          c2h(e1[0], e1[1]), c2h(e1[2], e1[3]));
            Y[tt][1] = h8(c2h(e2[0], e2[1]), c2h(e2[2], e2[3]),
                          q0 ? c2h(g0v, g1v) : h2z, h2z);
            A[tt][0] = Y[tt][0];
            A[tt][1] = setw(Y[tt][1], q0, pk2h(0.f, 1.f));   // t=0, bias-1
        }
    }

    // ---------------- RK4 (16 stages, zero LDS, packed f16x8) ----------
    const float hh = 1.0f / NSTEPS;
    float t0 = 0.0f;
    const unsigned one2 = 0x3C003C00u;   // f16 (1.0, 1.0)

#pragma clang loop unroll(disable)
    for (int stage = 0; stage < 4 * NSTEPS; ++stage) {
        const int s = stage & 3;

        f32x4 hc[2][4];
#pragma unroll
        for (int ct = 0; ct < 4; ++ct) {
            f32x4 c0 = __builtin_amdgcn_mfma_f32_16x16x32_f16(w1f[0][ct], A[0][0], zero4, 0, 0, 0);
            f32x4 c1 = __builtin_amdgcn_mfma_f32_16x16x32_f16(w1f[0][ct], A[1][0], zero4, 0, 0, 0);
            hc[0][ct] = __builtin_amdgcn_mfma_f32_16x16x32_f16(w1f[1][ct], A[0][1], c0, 0, 0, 0);
            hc[1][ct] = __builtin_amdgcn_mfma_f32_16x16x32_f16(w1f[1][ct], A[1][1], c1, 0, 0, 0);
        }
        f16x8 H[2][2];
#pragma unroll
        for (int tt = 0; tt < 2; ++tt) {
            H[tt][0] = h8(relu2(c2h(hc[tt][0][0], hc[tt][0][1])),
                          relu2(c2h(hc[tt][0][2], hc[tt][0][3])),
                          relu2(c2h(hc[tt][1][0], hc[tt][1][1])),
                          relu2(c2h(hc[tt][1][2], hc[tt][1][3])));
            f16x8 h1 = h8(relu2(c2h(hc[tt][2][0], hc[tt][2][1])),
                          relu2(c2h(hc[tt][2][2], hc[tt][2][3])),
                          relu2(c2h(hc[tt][3][0], hc[tt][3][1])),
                          relu2(c2h(hc[tt][3][2], hc[tt][3][3])));
            H[tt][1] = setw(h1, q0, one2);   // hidden bias slot (dim 50) = 1
        }
        f32x4 kc[2][4];
#pragma unroll
        for (int ct = 0; ct < 4; ++ct) {
            f32x4 c0 = __builtin_amdgcn_mfma_f32_16x16x32_f16(w2f[0][ct], H[0][0], zero4, 0, 0, 0);
            f32x4 c1 = __builtin_amdgcn_mfma_f32_16x16x32_f16(w2f[0][ct], H[1][0], zero4, 0, 0, 0);
            kc[0][ct] = __builtin_amdgcn_mfma_f32_16x16x32_f16(w2f[1][ct], H[0][1], c0, 0, 0, 0);
            kc[1][ct] = __builtin_amdgcn_mfma_f32_16x16x32_f16(w2f[1][ct], H[1][1], c1, 0, 0, 0);
        }

        const float ca = (s == 0 || s == 3) ? hh / 6.0f : hh / 3.0f;
        const float cb = (s == 2) ? hh : 0.5f * hh;
        const f16x2 cah = c2h(ca, ca);
        const f16x2 cbh = c2h(cb, cb);
        const f16x8 ca8 = h8(cah, cah, cah, cah);
        const f16x8 cb8 = h8(cbh, cbh, cbh, cbh);
        float tn;
        if (s < 3) tn = t0 + cb;
        else { t0 += hh; tn = t0; }
        const unsigned tw = pk2h(tn, 1.0f);

#pragma unroll
        for (int tt = 0; tt < 2; ++tt) {
            f16x8 KC0 = h8(c2h(kc[tt][0][0], kc[tt][0][1]), c2h(kc[tt][0][2], kc[tt][0][3]),
                           c2h(kc[tt][1][0], kc[tt][1][1]), c2h(kc[tt][1][2], kc[tt][1][3]));
            f16x8 KC1 = h8(c2h(kc[tt][2][0], kc[tt][2][1]), c2h(kc[tt][2][2], kc[tt][2][3]),
                           c2h(kc[tt][3][0], kc[tt][3][1]), c2h(kc[tt][3][2], kc[tt][3][3]));
            if (s == 0) {
                ACC[tt][0] = ca8 * KC0 + Y[tt][0];
                ACC[tt][1] = ca8 * KC1 + Y[tt][1];
            } else {
                ACC[tt][0] = ca8 * KC0 + ACC[tt][0];
                ACC[tt][1] = ca8 * KC1 + ACC[tt][1];
            }
            f16x8 av0, av1;
            if (s < 3) {
                av0 = cb8 * KC0 + Y[tt][0];
                av1 = cb8 * KC1 + Y[tt][1];
            } else {
                Y[tt][0] = ACC[tt][0];
                Y[tt][1] = ACC[tt][1];
                av0 = ACC[tt][0];
                av1 = ACC[tt][1];
            }
            A[tt][0] = av0;
            A[tt][1] = setw(av1, q0, tw);
        }
    }

    // ------------- decoder (4 f16 MFMAs per tile; weights loaded HERE) -------
    const f16x8 dw1 = *(const f16x8*)(const void*)(wg + 9216 + m * 32 + q * 8);
    const f16x8 dw2 = *(const f16x8*)(const void*)(wg + 9728 + m * 32 + q * 8);
    const f16x8 ow0 = *(const f16x8*)(const void*)(wg + 10240 + m * 64 + q * 8);
    const f16x8 ow1 = *(const f16x8*)(const void*)(wg + 10240 + m * 64 + 32 + q * 8);
    f32x4 bO, bD1, bD2;
    float w3v[4];
#pragma unroll
    for (int r = 0; r < 4; ++r) {
        bO[r]  = node_out_b[q * 4 + r];
        bD1[r] = dec_n_b1[q * 4 + r];
        bD2[r] = dec_n_b2[q * 4 + r];
        w3v[r] = dec_n_w3[q * 4 + r];
    }

#pragma unroll
    for (int tt = 0; tt < 2; ++tt) {
        f32x4 nl2 = __builtin_amdgcn_mfma_f32_16x16x32_f16(ow0, Y[tt][0], bO, 0, 0, 0);
        nl2       = __builtin_amdgcn_mfma_f32_16x16x32_f16(ow1, Y[tt][1], nl2, 0, 0, 0);

        *(uint2*)(dscrw + m * 40 + q * 4) =
            make_uint2(pk2h(nl2[0], nl2[1]), pk2h(nl2[2], nl2[3]));
        f16x8 nB = *(const f16x8*)(const void*)(dscrw + m * 40 + q * 8);
        f32x4 dh = __builtin_amdgcn_mfma_f32_16x16x32_f16(dw1, nB, bD1, 0, 0, 0);
#pragma unroll
        for (int r = 0; r < 4; ++r) dh[r] = swishf(dh[r]);

        *(uint2*)(dscrw + m * 40 + q * 4) =
            make_uint2(pk2h(dh[0], dh[1]), pk2h(dh[2], dh[3]));
        f16x8 dB = *(const f16x8*)(const void*)(dscrw + m * 40 + q * 8);
        f32x4 dh2 = __builtin_amdgcn_mfma_f32_16x16x32_f16(dw2, dB, bD2, 0, 0, 0);
#pragma unroll
        for (int r = 0; r < 4; ++r) dh2[r] = swishf(dh2[r]);

        float p = dh2[0] * w3v[0];
        p = fmaf(dh2[1], w3v[1], p);
        p = fmaf(dh2[2], w3v[2], p);
        p = fmaf(dh2[3], w3v[3], p);
        p += __shfl_xor(p, 16);
        p += __shfl_xor(p, 32);
        p += dec_n_b3[0];

        const int node = nd[tt];
        if (q0 && node < NN) {
            const float cur_pos = nodes[node * 5 + 0];
            const float c2 = nodes[node * 5 + 2];
            const float c3 = nodes[node * 5 + 3];
            const float cur_vel = nodes[node * 5 + 4];
            const float next_vel = fmaf(p, DTC, cur_vel);
            const float next_pos = fmaf(next_vel, DTC, cur_pos);
            out[node * 6 + 0] = next_pos;
            out[node * 6 + 1] = c2;
            out[node * 6 + 2] = c3;
            out[node * 6 + 3] = cur_vel;
            out[node * 6 + 4] = next_vel;
            out[node * 6 + 5] = p;
            npos[node] = next_pos;
        }
    }
}

// third pass: next_edges = diff(next_pos) from packed npos (coalesced), g_new
__global__ void gnode_edges(const float* __restrict__ npos,
                            float* __restrict__ out,
                            const float* __restrict__ g)
{
    const int e = blockIdx.x * blockDim.x + threadIdx.x;
    if (e < EE) {
        out[NN * 6 + e] = npos[e + 1] - npos[e];
    }
    if (e == 0) {
        out[NN * 6 + EE]     = g[0] + 1.0f;
        out[NN * 6 + EE + 1] = g[1];
    }
}

extern "C" void kernel_launch(void* const* d_in, const int* in_sizes, int n_in,
                              void* d_out, int out_size, void* d_ws, size_t ws_size,
                              hipStream_t stream) {
    const float* nodes      = (const float*)d_in[0];
    const float* edges      = (const float*)d_in[1];
    const float* g          = (const float*)d_in[2];
    const float* enc_n_w1   = (const float*)d_in[3];
    const float* enc_n_b1   = (const float*)d_in[4];
    const float* enc_n_w2   = (const float*)d_in[5];
    const float* enc_n_b2   = (const float*)d_in[6];
    const float* enc_e_w1   = (const float*)d_in[7];
    const float* enc_e_b1   = (const float*)d_in[8];
    const float* enc_e_w2   = (const float*)d_in[9];
    const float* enc_e_b2   = (const float*)d_in[10];
    const float* ode_w1     = (const float*)d_in[11];
    const float* ode_b1     = (const float*)d_in[12];
    const float* ode_w2     = (const float*)d_in[13];
    const float* ode_b2     = (const float*)d_in[14];
    const float* node_out_w = (const float*)d_in[15];
    const float* node_out_b = (const float*)d_in[16];
    const float* dec_n_w1   = (const float*)d_in[17];
    const float* dec_n_b1   = (const float*)d_in[18];
    const float* dec_n_w2   = (const float*)d_in[19];
    const float* dec_n_b2   = (const float*)d_in[20];
    const float* dec_n_w3   = (const float*)d_in[21];
    const float* dec_n_b3   = (const float*)d_in[22];
    float* out  = (float*)d_out;
    float* npos = (float*)d_ws;                               // NN floats
    unsigned short* wg = (unsigned short*)((char*)d_ws + (size_t)NN * 4);  // 22.5 KB

    gnode_weights<<<11, 256, 0, stream>>>(
        ode_w1, ode_b1, ode_w2, ode_b2,
        enc_n_w2, enc_e_w2, dec_n_w1, dec_n_w2, node_out_w, wg);

    gnode_main<<<GRID, 256, 0, stream>>>(
        nodes, edges, g,
        enc_n_w1, enc_n_b1, enc_n_b2,
        enc_e_w1, enc_e_b1, enc_e_b2,
        node_out_b, dec_n_b1, dec_n_b2, dec_n_w3, dec_n_b3,
        wg, out, npos);

    gnode_edges<<<(EE + 255) / 256, 256, 0, stream>>>(npos, out, g);
}

// Round 18
// 173.317 us; speedup vs baseline: 1.2480x; 1.2480x over previous
//
#include <hip/hip_runtime.h>

#define NN 200000
#define EE (NN - 1)
#define NSTEPS 4
#define DTC 0.01f
#define WPB 4
#define NPB 128           // nodes per block (2 tiles of 16 per wave x 4 waves)
#define GRID 1563         // ceil(200000/128)

typedef __attribute__((ext_vector_type(8))) _Float16 f16x8;
typedef __attribute__((ext_vector_type(2))) _Float16 f16x2;
typedef __attribute__((ext_vector_type(4))) float f32x4;

struct H4 { f16x2 a, b, c, d; };

__device__ __forceinline__ f16x2 c2h(float lo, float hi) {
    return __builtin_bit_cast(f16x2, __builtin_amdgcn_cvt_pkrtz(lo, hi)); // 1 instr
}
__device__ __forceinline__ unsigned pk2h(float lo, float hi) {
    return __builtin_bit_cast(unsigned, __builtin_amdgcn_cvt_pkrtz(lo, hi));
}
__device__ __forceinline__ f16x8 h8(f16x2 a, f16x2 b, f16x2 c, f16x2 d) {
    H4 t{a, b, c, d};
    return __builtin_bit_cast(f16x8, t);
}
__device__ __forceinline__ f16x2 relu2(f16x2 v) {   // v_pk_max_f16 vs 0
    f16x2 r;
    asm("v_pk_max_f16 %0, %1, 0" : "=v"(r) : "v"(v));
    return r;
}
__device__ __forceinline__ float swishf(float x) { return x / (1.0f + __expf(-x)); }

// dimension relabeling (verified R8+): C output (ct,q,r) packs directly into
// the next GEMM's B operand slots; B pos k <-> original dim permk(k).
__device__ __forceinline__ int permk(int k) {
    return (k & 0x23) | ((k & 4) << 2) | ((k & 0x18) >> 1);
}

// set dword 3 (f16 pair 3) of an f16x8 where cond holds: 1 v_cndmask
__device__ __forceinline__ f16x8 setw(f16x8 v, bool cond, unsigned nw) {
    uint4 u = __builtin_bit_cast(uint4, v);
    u.w = cond ? nw : u.w;
    return __builtin_bit_cast(f16x8, u);
}

// ws layout (ushort offsets within the weight region):
// [0,4096) w1s ; [4096,8192) w2s ; [8192,8704) encN ; [8704,9216) encE ;
// [9216,9728) dW1 ; [9728,10240) dW2 ; [10240,11264) outW
__global__ void gnode_weights(const float* __restrict__ ode_w1, const float* __restrict__ ode_b1,
                              const float* __restrict__ ode_w2, const float* __restrict__ ode_b2,
                              const float* __restrict__ enc_n_w2, const float* __restrict__ enc_e_w2,
                              const float* __restrict__ dec_n_w1, const float* __restrict__ dec_n_w2,
                              const float* __restrict__ node_out_w,
                              unsigned short* __restrict__ wg)
{
    const int b = blockIdx.x;
    const int tid = threadIdx.x;
    if (b < 8) {                     // W1ext^T / W2ext^T, permuted columns
        const int i = tid + b * 256;
        const int od = i >> 5;
        const int k2 = (i & 31) * 2;
        const int s0 = permk(k2);
        const int s1 = s0 + 1;
        float a0 = 0.f, a1 = 0.f, b0 = 0.f, b1 = 0.f;
        if (od < 50) {
            a0 = (s0 <= 50) ? ode_w1[s0 * 50 + od] : 0.f;
            a1 = (s1 <= 50) ? ode_w1[s1 * 50 + od]
                            : ((s1 == 51) ? ode_b1[od] : 0.f);
            b0 = (s0 < 50) ? ode_w2[s0 * 50 + od]
                           : ((s0 == 50) ? ode_b2[od] : 0.f);
            b1 = (s1 < 50) ? ode_w2[s1 * 50 + od] : 0.f;
        }
        *(unsigned*)(wg + od * 64 + k2) = pk2h(a0, a1);
        *(unsigned*)(wg + 4096 + od * 64 + k2) = pk2h(b0, b1);
    } else if (b < 10) {             // node_out_w^T 16x64, permuted cols
        const int i = tid + (b - 8) * 256;
        const int mm = i >> 5;
        const int kp = (i & 31) * 2;
        const int s0 = permk(kp);
        const float v0 = (s0     < 50) ? node_out_w[s0 * 16 + mm] : 0.f;
        const float v1 = (s0 + 1 < 50) ? node_out_w[(s0 + 1) * 16 + mm] : 0.f;
        *(unsigned*)(wg + 10240 + mm * 64 + kp) = pk2h(v0, v1);
    } else {                         // enc/dec 16x32 tiles, natural k (k>=16 zero)
        const int mm = tid >> 4;
        const int kp = (tid & 15) * 2;
        const bool rl = (kp < 16);
        const float eN0 = rl ? enc_n_w2[kp * 16 + mm] : 0.f;
        const float eN1 = rl ? enc_n_w2[(kp + 1) * 16 + mm] : 0.f;
        const float eE0 = rl ? enc_e_w2[kp * 16 + mm] : 0.f;
        const float eE1 = rl ? enc_e_w2[(kp + 1) * 16 + mm] : 0.f;
        const float d10 = rl ? dec_n_w1[kp * 16 + mm] : 0.f;
        const float d11 = rl ? dec_n_w1[(kp + 1) * 16 + mm] : 0.f;
        const float d20 = rl ? dec_n_w2[kp * 16 + mm] : 0.f;
        const float d21 = rl ? dec_n_w2[(kp + 1) * 16 + mm] : 0.f;
        *(unsigned*)(wg + 8192 + mm * 32 + kp) = pk2h(eN0, eN1);
        *(unsigned*)(wg + 8704 + mm * 32 + kp) = pk2h(eE0, eE1);
        *(unsigned*)(wg + 9216 + mm * 32 + kp) = pk2h(d10, d11);
        *(unsigned*)(wg + 9728 + mm * 32 + kp) = pk2h(d20, d21);
    }
}

// R18 = R16 verbatim (best known: main 74 us, VGPR=80, no spills).
// launch_bounds(256,3) is the unique spill-free point: caps <=128 total regs
// (R13/R15/R17) flip the allocator into 64-VGPR + 60-100 MB scratch mode.
__global__ __launch_bounds__(256, 3)
void gnode_main(const float* __restrict__ nodes,
                const float* __restrict__ edges,
                const float* __restrict__ g,
                const float* __restrict__ enc_n_w1, const float* __restrict__ enc_n_b1,
                const float* __restrict__ enc_n_b2,
                const float* __restrict__ enc_e_w1, const float* __restrict__ enc_e_b1,
                const float* __restrict__ enc_e_b2,
                const float* __restrict__ node_out_b,
                const float* __restrict__ dec_n_b1, const float* __restrict__ dec_n_b2,
                const float* __restrict__ dec_n_w3, const float* __restrict__ dec_n_b3,
                const unsigned short* __restrict__ wg,
                float* __restrict__ out, float* __restrict__ npos)
{
    __shared__ __attribute__((aligned(16))) unsigned short dscr[WPB][640];

    const int tid  = threadIdx.x;
    const int lane = tid & 63;
    const int wave = __builtin_amdgcn_readfirstlane(tid >> 6);
    const int m = lane & 15;
    const int q = lane >> 4;
    const bool q0 = (q == 0);
    unsigned short* const dscrw = &dscr[wave][0];

    int nd[2], nc[2];
    nd[0] = blockIdx.x * NPB + wave * 32 + m;
    nd[1] = nd[0] + 16;
    nc[0] = (nd[0] < NN) ? nd[0] : (NN - 1);
    nc[1] = (nd[1] < NN) ? nd[1] : (NN - 1);

    // zero decoder-scratch k=16..31 (dw1/dw2 A-rows are zero there, but LDS
    // garbage could be NaN; 0 * NaN != 0)
    *(uint2*)(dscrw + m * 40 + 16 + q * 4) = make_uint2(0u, 0u);

    // ====== pin ODE weight A-frags (the ONLY loop-live weight registers) =====
    f16x8 w1f[2][4], w2f[2][4];
#pragma unroll
    for (int kt = 0; kt < 2; ++kt)
#pragma unroll
        for (int ct = 0; ct < 4; ++ct) {
            const int od = ct * 16 + m;
            w1f[kt][ct] = *(const f16x8*)(const void*)(wg + od * 64 + kt * 32 + q * 8);
            w2f[kt][ct] = *(const f16x8*)(const void*)(wg + 4096 + od * 64 + kt * 32 + q * 8);
        }

    const f32x4 zero4 = {0.f, 0.f, 0.f, 0.f};
    const f16x2 h2z = {(_Float16)0.f, (_Float16)0.f};
    const f16x8 z8 = h8(h2z, h2z, h2z, h2z);

    // state: Y/ACC/A as whole f16x8 (2 per tile). pair 3 of [..][1] holds the
    // special slots (dims 50,51 = t, bias-1) on q0 lanes.
    f16x8 Y[2][2], ACC[2][2], A[2][2];

    // ---------------- encoder (3 f16 MFMAs per tile) ----------------
    {
        const f16x8 wNf = *(const f16x8*)(const void*)(wg + 8192 + m * 32 + q * 8);
        const f16x8 wEf = *(const f16x8*)(const void*)(wg + 8704 + m * 32 + q * 8);
        f32x4 bN, bE;
#pragma unroll
        for (int r = 0; r < 4; ++r) { bN[r] = enc_n_b2[q * 4 + r]; bE[r] = enc_e_b2[q * 4 + r]; }
        const float g0v = g[0], g1v = g[1];

#pragma unroll
        for (int tt = 0; tt < 2; ++tt) {
            const int node = nc[tt];
            f32x4 e0, e1, e2;
            {
                float nf[5];
#pragma unroll
                for (int c = 0; c < 5; ++c) nf[c] = nodes[node * 5 + c];
                f16x8 bfr = z8;
                if (q < 2) {
                    float hv[8];
#pragma unroll
                    for (int j = 0; j < 8; ++j) {
                        const int d = q * 8 + j;
                        float s = enc_n_b1[d];
#pragma unroll
                        for (int c = 0; c < 5; ++c) s = fmaf(nf[c], enc_n_w1[c * 16 + d], s);
                        hv[j] = swishf(s);
                    }
                    bfr = h8(c2h(hv[0], hv[1]), c2h(hv[2], hv[3]),
                             c2h(hv[4], hv[5]), c2h(hv[6], hv[7]));
                }
                e0 = __builtin_amdgcn_mfma_f32_16x16x32_f16(wNf, bfr, bN, 0, 0, 0);
            }
            {
                const float ev = (node < EE) ? edges[node] : 0.0f;
                f16x8 bfr = z8;
                if (q < 2) {
                    float hv[8];
#pragma unroll
                    for (int j = 0; j < 8; ++j) {
                        const int d = q * 8 + j;
                        hv[j] = swishf(fmaf(ev, enc_e_w1[d], enc_e_b1[d]));
                    }
                    bfr = h8(c2h(hv[0], hv[1]), c2h(hv[2], hv[3]),
                             c2h(hv[4], hv[5]), c2h(hv[6], hv[7]));
                }
                e1 = __builtin_amdgcn_mfma_f32_16x16x32_f16(wEf, bfr, bE, 0, 0, 0);
                if (node == NN - 1) e1 = zero4;
            }
            {
                const float ev = (node > 0) ? edges[node - 1] : 0.0f;
                f16x8 bfr = z8;
                if (q < 2) {
                    float hv[8];
#pragma unroll
                    for (int j = 0; j < 8; ++j) {
                        const int d = q * 8 + j;
                        hv[j] = swishf(fmaf(ev, enc_e_w1[d], enc_e_b1[d]));
                    }
                    bfr = h8(c2h(hv[0], hv[1]), c2h(hv[2], hv[3]),
                             c2h(hv[4], hv[5]), c2h(hv[6], hv[7]));
                }
                e2 = __builtin_amdgcn_mfma_f32_16x16x32_f16(wEf, bfr, bE, 0, 0, 0);
                if (node == 0) e2 = zero4;
            }
            Y[tt][0] = h8(c2h(e0[0], e0[1]), c2h(e0[2], e0[3]),
                          c2h(e1[0], e1[1]), c2h(e1[2], e1[3]));
            Y[tt][1] = h8(c2h(e2[0], e2[1]), c2h(e2[2], e2[3]),
                          q0 ? c2h(g0v, g1v) : h2z, h2z);
            A[tt][0] = Y[tt][0];
            A[tt][1] = setw(Y[tt][1], q0, pk2h(0.f, 1.f));   // t=0, bias-1
        }
    }

    // ---------------- RK4 (16 stages, zero LDS, packed f16x8) ----------
    const float hh = 1.0f / NSTEPS;
    float t0 = 0.0f;
    const unsigned one2 = 0x3C003C00u;   // f16 (1.0, 1.0)

#pragma clang loop unroll(disable)
    for (int stage = 0; stage < 4 * NSTEPS; ++stage) {
        const int s = stage & 3;

        f32x4 hc[2][4];
#pragma unroll
        for (int ct = 0; ct < 4; ++ct) {
            f32x4 c0 = __builtin_amdgcn_mfma_f32_16x16x32_f16(w1f[0][ct], A[0][0], zero4, 0, 0, 0);
            f32x4 c1 = __builtin_amdgcn_mfma_f32_16x16x32_f16(w1f[0][ct], A[1][0], zero4, 0, 0, 0);
            hc[0][ct] = __builtin_amdgcn_mfma_f32_16x16x32_f16(w1f[1][ct], A[0][1], c0, 0, 0, 0);
            hc[1][ct] = __builtin_amdgcn_mfma_f32_16x16x32_f16(w1f[1][ct], A[1][1], c1, 0, 0, 0);
        }
        f16x8 H[2][2];
#pragma unroll
        for (int tt = 0; tt < 2; ++tt) {
            H[tt][0] = h8(relu2(c2h(hc[tt][0][0], hc[tt][0][1])),
                          relu2(c2h(hc[tt][0][2], hc[tt][0][3])),
                          relu2(c2h(hc[tt][1][0], hc[tt][1][1])),
                          relu2(c2h(hc[tt][1][2], hc[tt][1][3])));
            f16x8 h1 = h8(relu2(c2h(hc[tt][2][0], hc[tt][2][1])),
                          relu2(c2h(hc[tt][2][2], hc[tt][2][3])),
                          relu2(c2h(hc[tt][3][0], hc[tt][3][1])),
                          relu2(c2h(hc[tt][3][2], hc[tt][3][3])));
            H[tt][1] = setw(h1, q0, one2);   // hidden bias slot (dim 50) = 1
        }
        f32x4 kc[2][4];
#pragma unroll
        for (int ct = 0; ct < 4; ++ct) {
            f32x4 c0 = __builtin_amdgcn_mfma_f32_16x16x32_f16(w2f[0][ct], H[0][0], zero4, 0, 0, 0);
            f32x4 c1 = __builtin_amdgcn_mfma_f32_16x16x32_f16(w2f[0][ct], H[1][0], zero4, 0, 0, 0);
            kc[0][ct] = __builtin_amdgcn_mfma_f32_16x16x32_f16(w2f[1][ct], H[0][1], c0, 0, 0, 0);
            kc[1][ct] = __builtin_amdgcn_mfma_f32_16x16x32_f16(w2f[1][ct], H[1][1], c1, 0, 0, 0);
        }

        const float ca = (s == 0 || s == 3) ? hh / 6.0f : hh / 3.0f;
        const float cb = (s == 2) ? hh : 0.5f * hh;
        const f16x2 cah = c2h(ca, ca);
        const f16x2 cbh = c2h(cb, cb);
        const f16x8 ca8 = h8(cah, cah, cah, cah);
        const f16x8 cb8 = h8(cbh, cbh, cbh, cbh);
        float tn;
        if (s < 3) tn = t0 + cb;
        else { t0 += hh; tn = t0; }
        const unsigned tw = pk2h(tn, 1.0f);

#pragma unroll
        for (int tt = 0; tt < 2; ++tt) {
            f16x8 KC0 = h8(c2h(kc[tt][0][0], kc[tt][0][1]), c2h(kc[tt][0][2], kc[tt][0][3]),
                           c2h(kc[tt][1][0], kc[tt][1][1]), c2h(kc[tt][1][2], kc[tt][1][3]));
            f16x8 KC1 = h8(c2h(kc[tt][2][0], kc[tt][2][1]), c2h(kc[tt][2][2], kc[tt][2][3]),
                           c2h(kc[tt][3][0], kc[tt][3][1]), c2h(kc[tt][3][2], kc[tt][3][3]));
            if (s == 0) {
                ACC[tt][0] = ca8 * KC0 + Y[tt][0];
                ACC[tt][1] = ca8 * KC1 + Y[tt][1];
            } else {
                ACC[tt][0] = ca8 * KC0 + ACC[tt][0];
                ACC[tt][1] = ca8 * KC1 + ACC[tt][1];
            }
            f16x8 av0, av1;
            if (s < 3) {
                av0 = cb8 * KC0 + Y[tt][0];
                av1 = cb8 * KC1 + Y[tt][1];
            } else {
                Y[tt][0] = ACC[tt][0];
                Y[tt][1] = ACC[tt][1];
                av0 = ACC[tt][0];
                av1 = ACC[tt][1];
            }
            A[tt][0] = av0;
            A[tt][1] = setw(av1, q0, tw);
        }
    }

    // ------------- decoder (4 f16 MFMAs per tile; weights loaded HERE) -------
    const f16x8 dw1 = *(const f16x8*)(const void*)(wg + 9216 + m * 32 + q * 8);
    const f16x8 dw2 = *(const f16x8*)(const void*)(wg + 9728 + m * 32 + q * 8);
    const f16x8 ow0 = *(const f16x8*)(const void*)(wg + 10240 + m * 64 + q * 8);
    const f16x8 ow1 = *(const f16x8*)(const void*)(wg + 10240 + m * 64 + 32 + q * 8);
    f32x4 bO, bD1, bD2;
    float w3v[4];
#pragma unroll
    for (int r = 0; r < 4; ++r) {
        bO[r]  = node_out_b[q * 4 + r];
        bD1[r] = dec_n_b1[q * 4 + r];
        bD2[r] = dec_n_b2[q * 4 + r];
        w3v[r] = dec_n_w3[q * 4 + r];
    }

#pragma unroll
    for (int tt = 0; tt < 2; ++tt) {
        f32x4 nl2 = __builtin_amdgcn_mfma_f32_16x16x32_f16(ow0, Y[tt][0], bO, 0, 0, 0);
        nl2       = __builtin_amdgcn_mfma_f32_16x16x32_f16(ow1, Y[tt][1], nl2, 0, 0, 0);

        *(uint2*)(dscrw + m * 40 + q * 4) =
            make_uint2(pk2h(nl2[0], nl2[1]), pk2h(nl2[2], nl2[3]));
        f16x8 nB = *(const f16x8*)(const void*)(dscrw + m * 40 + q * 8);
        f32x4 dh = __builtin_amdgcn_mfma_f32_16x16x32_f16(dw1, nB, bD1, 0, 0, 0);
#pragma unroll
        for (int r = 0; r < 4; ++r) dh[r] = swishf(dh[r]);

        *(uint2*)(dscrw + m * 40 + q * 4) =
            make_uint2(pk2h(dh[0], dh[1]), pk2h(dh[2], dh[3]));
        f16x8 dB = *(const f16x8*)(const void*)(dscrw + m * 40 + q * 8);
        f32x4 dh2 = __builtin_amdgcn_mfma_f32_16x16x32_f16(dw2, dB, bD2, 0, 0, 0);
#pragma unroll
        for (int r = 0; r < 4; ++r) dh2[r] = swishf(dh2[r]);

        float p = dh2[0] * w3v[0];
        p = fmaf(dh2[1], w3v[1], p);
        p = fmaf(dh2[2], w3v[2], p);
        p = fmaf(dh2[3], w3v[3], p);
        p += __shfl_xor(p, 16);
        p += __shfl_xor(p, 32);
        p += dec_n_b3[0];

        const int node = nd[tt];
        if (q0 && node < NN) {
            const float cur_pos = nodes[node * 5 + 0];
            const float c2 = nodes[node * 5 + 2];
            const float c3 = nodes[node * 5 + 3];
            const float cur_vel = nodes[node * 5 + 4];
            const float next_vel = fmaf(p, DTC, cur_vel);
            const float next_pos = fmaf(next_vel, DTC, cur_pos);
            out[node * 6 + 0] = next_pos;
            out[node * 6 + 1] = c2;
            out[node * 6 + 2] = c3;
            out[node * 6 + 3] = cur_vel;
            out[node * 6 + 4] = next_vel;
            out[node * 6 + 5] = p;
            npos[node] = next_pos;
        }
    }
}

// third pass: next_edges = diff(next_pos) from packed npos (coalesced), g_new
__global__ void gnode_edges(const float* __restrict__ npos,
                            float* __restrict__ out,
                            const float* __restrict__ g)
{
    const int e = blockIdx.x * blockDim.x + threadIdx.x;
    if (e < EE) {
        out[NN * 6 + e] = npos[e + 1] - npos[e];
    }
    if (e == 0) {
        out[NN * 6 + EE]     = g[0] + 1.0f;
        out[NN * 6 + EE + 1] = g[1];
    }
}

extern "C" void kernel_launch(void* const* d_in, const int* in_sizes, int n_in,
                              void* d_out, int out_size, void* d_ws, size_t ws_size,
                              hipStream_t stream) {
    const float* nodes      = (const float*)d_in[0];
    const float* edges      = (const float*)d_in[1];
    const float* g          = (const float*)d_in[2];
    const float* enc_n_w1   = (const float*)d_in[3];
    const float* enc_n_b1   = (const float*)d_in[4];
    const float* enc_n_w2   = (const float*)d_in[5];
    const float* enc_n_b2   = (const float*)d_in[6];
    const float* enc_e_w1   = (const float*)d_in[7];
    const float* enc_e_b1   = (const float*)d_in[8];
    const float* enc_e_w2   = (const float*)d_in[9];
    const float* enc_e_b2   = (const float*)d_in[10];
    const float* ode_w1     = (const float*)d_in[11];
    const float* ode_b1     = (const float*)d_in[12];
    const float* ode_w2     = (const float*)d_in[13];
    const float* ode_b2     = (const float*)d_in[14];
    const float* node_out_w = (const float*)d_in[15];
    const float* node_out_b = (const float*)d_in[16];
    const float* dec_n_w1   = (const float*)d_in[17];
    const float* dec_n_b1   = (const float*)d_in[18];
    const float* dec_n_w2   = (const float*)d_in[19];
    const float* dec_n_b2   = (const float*)d_in[20];
    const float* dec_n_w3   = (const float*)d_in[21];
    const float* dec_n_b3   = (const float*)d_in[22];
    float* out  = (float*)d_out;
    float* npos = (float*)d_ws;                               // NN floats
    unsigned short* wg = (unsigned short*)((char*)d_ws + (size_t)NN * 4);  // 22.5 KB

    gnode_weights<<<11, 256, 0, stream>>>(
        ode_w1, ode_b1, ode_w2, ode_b2,
        enc_n_w2, enc_e_w2, dec_n_w1, dec_n_w2, node_out_w, wg);

    gnode_main<<<GRID, 256, 0, stream>>>(
        nodes, edges, g,
        enc_n_w1, enc_n_b1, enc_n_b2,
        enc_e_w1, enc_e_b1, enc_e_b2,
        node_out_b, dec_n_b1, dec_n_b2, dec_n_w3, dec_n_b3,
        wg, out, npos);

    gnode_edges<<<(EE + 255) / 256, 256, 0, stream>>>(npos, out, g);
}